// Round 16
// baseline (1199.132 us; speedup 1.0000x reference)
//
#include <hip/hip_runtime.h>
#include <hip/hip_bf16.h>
#include <cstdint>
#include <cstddef>

// Problem dims (fixed)
constexpr int IC = 2048, IH = 16, OC = 64, OH = 32;
constexpr int NN = OC * OH;          // 2048 flattened (o,j)
constexpr int ICHUNK = 32;           // i's per chunk
constexpr int NCHUNK = IC / ICHUNK;  // 64
constexpr int BTILE = 16;            // routed-pass b-tile

typedef __attribute__((ext_vector_type(8))) short bf16x8;
typedef __attribute__((ext_vector_type(4))) float f32x4;
typedef __attribute__((ext_vector_type(16))) float f32x16;

// ---- routed-pass LDS (dynamic): F_Z zeros | per-wave W slices | T table ----
constexpr int F_Z = 0;                        // 64 B zeros (K-pad A-frag)
constexpr int F_W = 64;                       // 8 waves x 8 KiB single-buffer slices
constexpr int T_ROWF = 17;                    // floats per T row (8 used, odd pad)
constexpr int F_T = F_W + 65536;              // 65600
constexpr int F_SMEM = F_T + 2 * 16 * T_ROWF * 4;  // 67776 (2 blocks/CU fit)

__device__ __forceinline__ unsigned short f2bf(float f) {
    unsigned u = __float_as_uint(f);
    u += 0x7fffu + ((u >> 16) & 1u);          // round-to-nearest-even
    return (unsigned short)(u >> 16);
}
__device__ __forceinline__ float bf_lo(unsigned u) {
    return __uint_as_float(u << 16);
}
__device__ __forceinline__ float bf_hi(unsigned u) {
    return __uint_as_float(u & 0xffff0000u);
}
__device__ __forceinline__ unsigned pk2f(float a, float b) {
    return (unsigned)f2bf(a) | ((unsigned)f2bf(b) << 16);
}
__device__ __forceinline__ unsigned cvtpk(float lo, float hi) {
    unsigned r;
    asm("v_cvt_pk_bf16_f32 %0, %1, %2" : "=v"(r) : "v"(lo), "v"(hi));
    return r;
}
__device__ __forceinline__ void gload_lds16(const void* g, void* l) {
    __builtin_amdgcn_global_load_lds(
        (const __attribute__((address_space(1))) void*)g,
        (__attribute__((address_space(3))) void*)l, 16, 0, 0);
}

// Fused prep:
//   W fp32 [2048 i][16 h][2048 n] -> Wp bf16 [i][2048 n][16 h]  (32 B per n)
//   x  f32 [64 b][2048 i][16 h]   -> xs bf16 [2048 i][64 b][16 h]
__global__ void prep_wx(const float* __restrict__ W, unsigned short* __restrict__ Wp,
                        const float* __restrict__ x, unsigned short* __restrict__ xs) {
    int i = blockIdx.x;
    int t = threadIdx.x;            // 0..511, handles n = 4t..4t+3
    const float* wp = W + (size_t)i * (IH * NN);
    int n0 = t * 4;
    float4 row[16];
#pragma unroll
    for (int h = 0; h < 16; ++h) row[h] = *(const float4*)(wp + h * NN + n0);
    char* dst = (char*)Wp + (size_t)i * 65536;
#pragma unroll
    for (int q = 0; q < 4; ++q) {
        float v[16];
#pragma unroll
        for (int h = 0; h < 16; ++h) v[h] = ((const float*)&row[h])[q];
        uint4 lo, hi;
        lo.x = pk2f(v[0], v[1]);   lo.y = pk2f(v[2], v[3]);
        lo.z = pk2f(v[4], v[5]);   lo.w = pk2f(v[6], v[7]);
        hi.x = pk2f(v[8], v[9]);   hi.y = pk2f(v[10], v[11]);
        hi.z = pk2f(v[12], v[13]); hi.w = pk2f(v[14], v[15]);
        *(uint4*)(dst + (size_t)(n0 + q) * 32) = lo;
        *(uint4*)(dst + (size_t)(n0 + q) * 32 + 16) = hi;
    }
    if (t < 64) {
        const float* p = x + ((size_t)t * IC + i) * IH;
        unsigned short out[16];
#pragma unroll
        for (int h = 0; h < 16; ++h) out[h] = f2bf(p[h]);
        unsigned short* q = xs + ((size_t)i * 64 + t) * 16;
        *(uint4*)q = *(uint4*)&out[0];
        *(uint4*)(q + 8) = *(uint4*)&out[8];
    }
}

// ---------------- iteration-1 pass: plain GEMM, 32x32x16 MFMA ----------------
// S1[b,n] = (1/64) sum_i U[b,i,n]. HBM-bound on Wp read — at floor.
// Updated for the [i][n][16h] Wp layout (A-frag: (n)*32 + (lane>>5)*16).
__launch_bounds__(512, 4)
__global__ void uniform_gemm(const unsigned short* __restrict__ xs,
                             const unsigned short* __restrict__ Wp,
                             float* __restrict__ P) {
    __shared__ char smem[32768];          // 2 bufs x [512 n][32 B]
    const int tid = threadIdx.x;
    const int lane = tid & 63;
    const int wv = tid >> 6;              // 0..7
    const int l31 = lane & 31;
    const int hi = lane >> 5;

    const int v = blockIdx.x;
    const int chunk = (v & 7) + 8 * (v >> 6);   // same-chunk blocks share an XCD
    const int sub = (v >> 3) & 7;
    const int b0 = (sub >> 2) * 32;
    const int nq = sub & 3;
    const int i0 = chunk * ICHUNK;
    const int n0 = nq * 512;

    const char* gW = (const char*)Wp + (size_t)i0 * 65536 + n0 * 32;
    int goff[2], loff[2];
#pragma unroll
    for (int r = 0; r < 2; ++r) {
        goff[r] = r * 8192 + tid * 16;
        loff[r] = r * 8192 + tid * 16;
    }
    const int abase = wv * 2048 + l31 * 32 + hi * 16;   // A-frag per-lane base
    const char* gx = (const char*)xs + (size_t)i0 * 2048 + (b0 + l31) * 32 + hi * 16;

    // prologue: stage i0 -> buf0, load xf(i0)
#pragma unroll
    for (int r = 0; r < 2; ++r) gload_lds16(gW + goff[r], smem + loff[r]);
    bf16x8 xf = *(const bf16x8*)gx;
    __syncthreads();

    f32x16 sacc[2];
#pragma unroll
    for (int t = 0; t < 2; ++t)
#pragma unroll
        for (int k = 0; k < 16; ++k) sacc[t][k] = 0.f;

    for (int pp = 0; pp < ICHUNK / 2; ++pp) {
#pragma unroll
        for (int cb = 0; cb < 2; ++cb) {
            const int ii = pp * 2 + cb;
            bf16x8 xf_n = xf;
            if (ii + 1 < ICHUNK) {
                const char* gWn = gW + (size_t)(ii + 1) * 65536;
                char* nb = smem + (cb ^ 1) * 16384;
#pragma unroll
                for (int r = 0; r < 2; ++r) gload_lds16(gWn + goff[r], nb + loff[r]);
                xf_n = *(const bf16x8*)(gx + (size_t)(ii + 1) * 2048);
            }
            const char* ab = smem + cb * 16384 + abase;
#pragma unroll
            for (int t = 0; t < 2; ++t) {
                bf16x8 af = *(const bf16x8*)(ab + t * 1024);
                sacc[t] = __builtin_amdgcn_mfma_f32_32x32x16_bf16(af, xf, sacc[t], 0, 0, 0);
            }
            __syncthreads();   // drains this wave's gloads + fences buffer swap
            xf = xf_n;
        }
    }

    // write: D col = l31 -> b; row = (reg&3)+8*(reg>>2)+4*hi
    float* Pb = P + ((size_t)(chunk * 64) + b0 + l31) * NN + n0;
#pragma unroll
    for (int t = 0; t < 2; ++t) {
        int ntl = (wv * 2 + t) * 32;
#pragma unroll
        for (int q = 0; q < 4; ++q) {
            float4 o4;
            o4.x = sacc[t][4 * q + 0] * (1.0f / 64.0f);
            o4.y = sacc[t][4 * q + 1] * (1.0f / 64.0f);
            o4.z = sacc[t][4 * q + 2] * (1.0f / 64.0f);
            o4.w = sacc[t][4 * q + 3] * (1.0f / 64.0f);
            *(float4*)(Pb + ntl + 8 * q + 4 * hi) = o4;
        }
    }
}

// ---------------- routed pass v2: 512 thr, 8 waves, wave owns 8 o's ----------
// 2 blocks/CU (LDS 67 KB): independent barrier groups — the r5-uniform 3x
// lever. Per-wave single-buffered W slice (8 KB: wave wv only ever reads
// n in [wv*256, wv*256+256)) -> W needs NO cross-wave sync; ordering is
// wave-local s_waitcnt. One 8-wave T-barrier per iter (denominator exchange).
// C applied via a SECOND MFMA with C-scaled bf16 x-frag accumulating into
// sacc (C[b] sits on lane l15 for both D-cols and B-cols) — acc is transient.
__launch_bounds__(512, 4)
__global__ void routed_soft(const unsigned short* __restrict__ xs,
                            const unsigned short* __restrict__ Wp,
                            const float* __restrict__ Vin,
                            float* __restrict__ P) {
    extern __shared__ char smem[];
    const int tid = threadIdx.x;
    const int lane = tid & 63;
    const int wv = tid >> 6;              // 0..7, owns o in [wv*8, wv*8+8)
    const int l15 = lane & 15;
    const int g = lane >> 4;              // 0..3

    const int v = blockIdx.x;
    const int bt = (v >> 3) & 3;          // 4 b-tiles of a chunk share an XCD
    const int chunk = (v & 7) + 8 * (v >> 5);
    const int b0 = bt * BTILE;
    const int i0 = chunk * ICHUNK;

    // every wave zeroes F_Z (same values — benign) so no block sync needed
    if (lane < 16) ((unsigned*)(smem + F_Z))[lane] = 0u;

    // V (i-invariant): 8 o x 8 j per lane, packed bf16 (32 VGPR)
    uint4 vrp[8];
#pragma unroll
    for (int o8 = 0; o8 < 8; ++o8) {
        const float* vb = Vin + ((size_t)(b0 + l15) * OC + (wv * 8 + o8)) * OH + g * 4;
        f32x4 a = *(const f32x4*)vb;          // j = g*4..
        f32x4 c = *(const f32x4*)(vb + 16);   // j = 16+g*4..
        vrp[o8].x = pk2f(a.x, a.y); vrp[o8].y = pk2f(a.z, a.w);
        vrp[o8].z = pk2f(c.x, c.y); vrp[o8].w = pk2f(c.z, c.w);
    }

    char* ws = smem + F_W + wv * 8192;    // my wave's W slice
    const char* gWs = (const char*)Wp + (size_t)i0 * 65536 + wv * 8192;

    // prologue: stage my slice of W(i0); load xf(i0)
#pragma unroll
    for (int r = 0; r < 8; ++r)
        gload_lds16(gWs + r * 1024 + lane * 16, ws + r * 1024 + lane * 16);
    bf16x8 xf = *(const bf16x8*)((const char*)xs + (size_t)i0 * 2048 +
                                 (b0 + l15) * 32 + (g & 1) * 16);
    asm volatile("s_waitcnt lgkmcnt(0)" ::: "memory");   // F_Z zeros visible (own writes)

    const f32x4 fzero = {0.f, 0.f, 0.f, 0.f};
    f32x4 sacc[16];
#pragma unroll
    for (int t = 0; t < 16; ++t) sacc[t] = fzero;

    for (int ii = 0; ii < ICHUNK; ++ii) {
        const int cur = ii & 1;

        // my stage(W(ii)) + xf complete (wave-local; no block sync)
        asm volatile("s_waitcnt vmcnt(0)" ::: "memory");
        __builtin_amdgcn_sched_barrier(0);

        // ---- ph2: per-o8 MFMA1 + blog dot + exp (acc transient) ----
        float eb[8];
#pragma unroll
        for (int o8 = 0; o8 < 8; ++o8) {
            float p = 0.f;
#pragma unroll
            for (int jt = 0; jt < 2; ++jt) {
                int np = o8 * 32 + jt * 16 + l15;    // n' within my slice
                const char* aptr = (lane < 32)
                    ? (ws + np * 32 + g * 16)
                    : (smem + F_Z);
                bf16x8 af = *(const bf16x8*)aptr;
                f32x4 u = __builtin_amdgcn_mfma_f32_16x16x32_bf16(af, xf, fzero, 0, 0, 0);
                unsigned va = jt ? vrp[o8].z : vrp[o8].x;
                unsigned vb = jt ? vrp[o8].w : vrp[o8].y;
                p += u.x * bf_lo(va) + u.y * bf_hi(va) +
                     u.z * bf_lo(vb) + u.w * bf_hi(vb);
            }
            p += __shfl_xor(p, 16);
            p += __shfl_xor(p, 32);
            eb[o8] = __expf(p);      // no max subtraction (|Blog| <~ 12)
        }
        float s4 = ((eb[0] + eb[1]) + (eb[2] + eb[3])) +
                   ((eb[4] + eb[5]) + (eb[6] + eb[7]));
        if (lane < 16)
            *(float*)(smem + F_T + (cur * 16 + l15) * (T_ROWF * 4) + wv * 4) = s4;

        // ---- T-barrier (only block sync per iter): rule #18 fencing ----
        asm volatile("s_waitcnt lgkmcnt(0)" ::: "memory");
        __builtin_amdgcn_sched_barrier(0);
        __builtin_amdgcn_s_barrier();
        __builtin_amdgcn_sched_barrier(0);

        // ---- denominator for b=l15 ----
        const char* tr = smem + F_T + (cur * 16 + l15) * (T_ROWF * 4);
        f32x4 t0 = *(const f32x4*)(tr);
        f32x4 t1 = *(const f32x4*)(tr + 16);
        f32x4 ts = t0 + t1;
        float rd = __builtin_amdgcn_rcpf((ts.x + ts.y) + (ts.z + ts.w));

        // ---- ph6: per-o8 scale xf by C and MFMA2-accumulate into sacc ----
        unsigned xlo = ((unsigned*)&xf)[0], xhi = ((unsigned*)&xf)[1];
        unsigned xl2 = ((unsigned*)&xf)[2], xh2 = ((unsigned*)&xf)[3];
#pragma unroll
        for (int o8 = 0; o8 < 8; ++o8) {
            float c = eb[o8] * rd;
            bf16x8 xfs;
            ((unsigned*)&xfs)[0] = cvtpk(bf_lo(xlo) * c, bf_hi(xlo) * c);
            ((unsigned*)&xfs)[1] = cvtpk(bf_lo(xhi) * c, bf_hi(xhi) * c);
            ((unsigned*)&xfs)[2] = cvtpk(bf_lo(xl2) * c, bf_hi(xl2) * c);
            ((unsigned*)&xfs)[3] = cvtpk(bf_lo(xh2) * c, bf_hi(xh2) * c);
#pragma unroll
            for (int jt = 0; jt < 2; ++jt) {
                int np = o8 * 32 + jt * 16 + l15;
                const char* aptr = (lane < 32)
                    ? (ws + np * 32 + g * 16)
                    : (smem + F_Z);
                bf16x8 af = *(const bf16x8*)aptr;
                sacc[o8 * 2 + jt] = __builtin_amdgcn_mfma_f32_16x16x32_bf16(
                    af, xfs, sacc[o8 * 2 + jt], 0, 0, 0);
            }
        }

        // ---- my W-slice reads retired -> restage my slice for i+1 ----
        asm volatile("s_waitcnt lgkmcnt(0)" ::: "memory");
        __builtin_amdgcn_sched_barrier(0);
        if (ii + 1 < ICHUNK) {
            const char* gn = gWs + (size_t)(ii + 1) * 65536;
#pragma unroll
            for (int r = 0; r < 8; ++r)
                gload_lds16(gn + r * 1024 + lane * 16, ws + r * 1024 + lane * 16);
            xf = *(const bf16x8*)((const char*)xs + (size_t)(i0 + ii + 1) * 2048 +
                                  (b0 + l15) * 32 + (g & 1) * 16);
        }
    }

    // write partial S: P[chunk][b][n]; D rows g*4+q -> n = nt + g*4 + q
#pragma unroll
    for (int t = 0; t < 16; ++t) {
        int nt = (wv * 8 + (t >> 1)) * 32 + (t & 1) * 16 + g * 4;
        float* dst = P + ((size_t)(chunk * 64) + b0 + l15) * NN + nt;
        float4 o4;
        o4.x = sacc[t].x; o4.y = sacc[t].y; o4.z = sacc[t].z; o4.w = sacc[t].w;
        *(float4*)dst = o4;
    }
}

// Sum partials over chunks, squash over j, SET or ADD into dst.
__global__ void reduce_squash(const float* __restrict__ P, float* __restrict__ dst,
                              int addmode) {
    int pr = blockIdx.x * 2 + (threadIdx.x >> 5);  // (b,o) row 0..4095
    int j = threadIdx.x & 31;
    int b = pr >> 6, o = pr & 63;
    const float* p = P + (size_t)b * NN + o * 32 + j;
    float s = 0.f;
#pragma unroll 8
    for (int c = 0; c < NCHUNK; ++c) s += p[(size_t)c * (64 * NN)];
    float nsq = s * s;
#pragma unroll
    for (int d = 16; d >= 1; d >>= 1) nsq += __shfl_xor(nsq, d);
    float nrm = sqrtf(nsq);
    float f = nrm / (1.f + nsq);   // squash: x * ||x||/(1+||x||^2)
    float outv = s * f;
    int idx = pr * 32 + j;
    if (addmode) dst[idx] += outv;
    else dst[idx] = outv;
}

extern "C" void kernel_launch(void* const* d_in, const int* in_sizes, int n_in,
                              void* d_out, int out_size, void* d_ws, size_t ws_size,
                              hipStream_t stream) {
    const float* x = (const float*)d_in[0];   // [64][2048][16]
    const float* W = (const float*)d_in[1];   // [2048][16][64][32]
    float* out = (float*)d_out;               // [64][64][32]
    char* ws = (char*)d_ws;
    // ws: xs bf16 4 MiB | P f32 32 MiB @4M | Vsum 512 KiB @36M | Wp bf16 128 MiB @40M
    unsigned short* xs = (unsigned short*)ws;
    float* P = (float*)(ws + ((size_t)4 << 20));
    float* Vsum = (float*)(ws + ((size_t)36 << 20));
    unsigned short* Wp = (unsigned short*)(ws + (((size_t)40) << 20));

    (void)hipFuncSetAttribute(reinterpret_cast<const void*>(&routed_soft),
                              hipFuncAttributeMaxDynamicSharedMemorySize, F_SMEM);

    prep_wx<<<dim3(2048), dim3(512), 0, stream>>>(W, Wp, x, xs);
    // iter 1: uniform C = 1/64 -> plain GEMM -> S1 -> V1
    uniform_gemm<<<dim3(512), dim3(512), 0, stream>>>(xs, Wp, P);
    reduce_squash<<<dim3(2048), dim3(64), 0, stream>>>(P, Vsum, 0);
    // iter 2: Blog = U.V1 -> S2 -> V2 (Vsum = V1+V2)
    routed_soft<<<dim3(256), dim3(512), F_SMEM, stream>>>(xs, Wp, Vsum, P);
    reduce_squash<<<dim3(2048), dim3(64), 0, stream>>>(P, Vsum, 1);
    // iter 3: Blog = U.(V1+V2) -> S3 -> V3 = output
    routed_soft<<<dim3(256), dim3(512), F_SMEM, stream>>>(xs, Wp, Vsum, P);
    reduce_squash<<<dim3(2048), dim3(64), 0, stream>>>(P, out, 0);
}

// Round 17
// 288.535 us; speedup vs baseline: 4.1559x; 4.1559x over previous
//
#include <hip/hip_runtime.h>
#include <hip/hip_bf16.h>
#include <cstdint>
#include <cstddef>

// Problem dims (fixed)
constexpr int IC = 2048, IH = 16, OC = 64, OH = 32;
constexpr int NN = OC * OH;          // 2048 flattened (o,j)
constexpr int ICHUNK = 32;           // i's per chunk
constexpr int NCHUNK = IC / ICHUNK;  // 64
constexpr int BTILE = 16;            // routed-pass b-tile

typedef __attribute__((ext_vector_type(8))) short bf16x8;
typedef __attribute__((ext_vector_type(4))) float f32x4;
typedef __attribute__((ext_vector_type(16))) float f32x16;

// ---- routed-pass LDS layout (bytes), dynamic shared ----
constexpr int F_Z = 0;                        // 64 B zeros (K-pad A-frag, exact per-tile select)
constexpr int F_W = 2048;                     // double-buffered W: 2 x 64 KiB
constexpr int F_WBUF = 65536;                 // [2 slot][2048 n][8 h] bf16 per i
constexpr int F_T = F_W + 2 * F_WBUF;         // 133120: denom partials, 2 bufs
constexpr int T_ROW = 80;                     // bytes per b-row
constexpr int T_BUF = 16 * T_ROW;             // 1280 B
constexpr int F_SMEM = F_T + 2 * T_BUF;       // 135680 (< 160 KiB)

__device__ __forceinline__ unsigned short f2bf(float f) {
    unsigned u = __float_as_uint(f);
    u += 0x7fffu + ((u >> 16) & 1u);          // round-to-nearest-even
    return (unsigned short)(u >> 16);
}
__device__ __forceinline__ float bf_lo(unsigned u) {
    return __uint_as_float(u << 16);
}
__device__ __forceinline__ float bf_hi(unsigned u) {
    return __uint_as_float(u & 0xffff0000u);
}
__device__ __forceinline__ unsigned pk2f(float a, float b) {
    return (unsigned)f2bf(a) | ((unsigned)f2bf(b) << 16);
}
__device__ __forceinline__ void gload_lds16(const void* g, void* l) {
    __builtin_amdgcn_global_load_lds(
        (const __attribute__((address_space(1))) void*)g,
        (__attribute__((address_space(3))) void*)l, 16, 0, 0);
}

// Fused prep:
//   W fp32 [2048 i][16 h][2048 n] -> Wp bf16 [i][2 slot][2048 n][8 h]
//   x  f32 [64 b][2048 i][16 h]   -> xs bf16 [2048 i][64 b][16 h]
__global__ void prep_wx(const float* __restrict__ W, unsigned short* __restrict__ Wp,
                        const float* __restrict__ x, unsigned short* __restrict__ xs) {
    int i = blockIdx.x;
    int t = threadIdx.x;            // 0..511, handles n = 4t..4t+3
    const float* wp = W + (size_t)i * (IH * NN);
    int n0 = t * 4;
    float4 row[16];
#pragma unroll
    for (int h = 0; h < 16; ++h) row[h] = *(const float4*)(wp + h * NN + n0);
    char* dst = (char*)Wp + (size_t)i * 65536;
#pragma unroll
    for (int q = 0; q < 4; ++q) {
        float v[16];
#pragma unroll
        for (int h = 0; h < 16; ++h) v[h] = ((const float*)&row[h])[q];
        uint4 lo, hi;
        lo.x = pk2f(v[0], v[1]);   lo.y = pk2f(v[2], v[3]);
        lo.z = pk2f(v[4], v[5]);   lo.w = pk2f(v[6], v[7]);
        hi.x = pk2f(v[8], v[9]);   hi.y = pk2f(v[10], v[11]);
        hi.z = pk2f(v[12], v[13]); hi.w = pk2f(v[14], v[15]);
        *(uint4*)(dst + (size_t)(n0 + q) * 16) = lo;
        *(uint4*)(dst + 32768 + (size_t)(n0 + q) * 16) = hi;
    }
    if (t < 64) {
        const float* p = x + ((size_t)t * IC + i) * IH;
        unsigned short out[16];
#pragma unroll
        for (int h = 0; h < 16; ++h) out[h] = f2bf(p[h]);
        unsigned short* q = xs + ((size_t)i * 64 + t) * 16;
        *(uint4*)q = *(uint4*)&out[0];
        *(uint4*)(q + 8) = *(uint4*)&out[8];
    }
}

// ---------------- iteration-1 pass: plain GEMM, 32x32x16 MFMA ----------------
// S1[b,n] = (1/64) sum_i U[b,i,n]. No softmax -> blocks may split n freely.
__launch_bounds__(512, 4)
__global__ void uniform_gemm(const unsigned short* __restrict__ xs,
                             const unsigned short* __restrict__ Wp,
                             float* __restrict__ P) {
    __shared__ char smem[32768];          // 2 bufs x [2 slot][512 n][8 h] bf16
    const int tid = threadIdx.x;
    const int lane = tid & 63;
    const int wv = tid >> 6;              // 0..7
    const int l31 = lane & 31;
    const int hi = lane >> 5;

    const int v = blockIdx.x;
    const int chunk = (v & 7) + 8 * (v >> 6);   // same-chunk blocks share an XCD
    const int sub = (v >> 3) & 7;
    const int b0 = (sub >> 2) * 32;
    const int nq = sub & 3;
    const int i0 = chunk * ICHUNK;
    const int n0 = nq * 512;

    const char* gW = (const char*)Wp + (size_t)i0 * 65536;
    int goff[2], loff[2];
#pragma unroll
    for (int r = 0; r < 2; ++r) {
        int m = wv * 2 + r, s = m >> 3, q = m & 7;
        goff[r] = s * 32768 + n0 * 16 + q * 1024 + lane * 16;
        loff[r] = s * 8192 + q * 1024;
    }
    const int abase = hi * 8192 + wv * 1024 + l31 * 16;   // A-frag per-lane base
    const char* gx = (const char*)xs + (size_t)i0 * 2048 + (b0 + l31) * 32 + hi * 16;

    // prologue: stage i0 -> buf0, load xf(i0)
#pragma unroll
    for (int r = 0; r < 2; ++r) gload_lds16(gW + goff[r], smem + loff[r]);
    bf16x8 xf = *(const bf16x8*)gx;
    __syncthreads();

    f32x16 sacc[2];
#pragma unroll
    for (int t = 0; t < 2; ++t)
#pragma unroll
        for (int k = 0; k < 16; ++k) sacc[t][k] = 0.f;

    for (int pp = 0; pp < ICHUNK / 2; ++pp) {
#pragma unroll
        for (int cb = 0; cb < 2; ++cb) {
            const int ii = pp * 2 + cb;
            bf16x8 xf_n = xf;
            if (ii + 1 < ICHUNK) {
                const char* gWn = gW + (size_t)(ii + 1) * 65536;
                char* nb = smem + (cb ^ 1) * 16384;
#pragma unroll
                for (int r = 0; r < 2; ++r) gload_lds16(gWn + goff[r], nb + loff[r]);
                xf_n = *(const bf16x8*)(gx + (size_t)(ii + 1) * 2048);
            }
            const char* ab = smem + cb * 16384 + abase;
#pragma unroll
            for (int t = 0; t < 2; ++t) {
                bf16x8 af = *(const bf16x8*)(ab + t * 512);
                sacc[t] = __builtin_amdgcn_mfma_f32_32x32x16_bf16(af, xf, sacc[t], 0, 0, 0);
            }
            __syncthreads();   // drains this wave's gloads + fences buffer swap
            xf = xf_n;
        }
    }

    // write: D col = l31 -> b; row = (reg&3)+8*(reg>>2)+4*hi
    float* Pb = P + ((size_t)(chunk * 64) + b0 + l31) * NN + n0;
#pragma unroll
    for (int t = 0; t < 2; ++t) {
        int ntl = (wv * 2 + t) * 32;
#pragma unroll
        for (int q = 0; q < 4; ++q) {
            float4 o4;
            o4.x = sacc[t][4 * q + 0] * (1.0f / 64.0f);
            o4.y = sacc[t][4 * q + 1] * (1.0f / 64.0f);
            o4.z = sacc[t][4 * q + 2] * (1.0f / 64.0f);
            o4.w = sacc[t][4 * q + 3] * (1.0f / 64.0f);
            *(float4*)(Pb + ntl + 8 * q + 4 * hi) = o4;
        }
    }
}

// ---------------- routed pass (iters 2,3): 16 waves, wave owns 4 o's ----------
// r4-style TRANSIENT addressing (recomputed per use, short live ranges): the
// hoisted-pointer / wider-tile variants (r5-r12, r15, r16) all blew the 64
// arch-VGPR cliff or the memory system. One __syncthreads per i; softmax =
// exp in-lane (no max; |Blog| <~ 12), denominator via tiny LDS table.
__launch_bounds__(1024, 4)
__global__ void routed_soft(const unsigned short* __restrict__ xs,
                            const unsigned short* __restrict__ Wp,
                            const float* __restrict__ Vin,
                            float* __restrict__ P) {
    extern __shared__ char smem[];
    const int tid = threadIdx.x;
    const int lane = tid & 63;
    const int wv = tid >> 6;              // 0..15, owns o in [wv*4, wv*4+4)
    const int l15 = lane & 15;
    const int g = lane >> 4;              // 0..3

    const int v = blockIdx.x;
    const int bt = (v >> 3) & 3;          // 4 b-tiles of a chunk share an XCD
    const int chunk = (v & 7) + 8 * (v >> 5);
    const int b0 = bt * BTILE;
    const int i0 = chunk * ICHUNK;

    if (tid < 16) ((unsigned*)(smem + F_Z))[tid] = 0u;   // 64 B zero frag

    // V (i-invariant): 4 o x 8 j per lane, packed bf16
    uint4 vrp[4];
#pragma unroll
    for (int o8 = 0; o8 < 4; ++o8) {
        const float* vb = Vin + ((size_t)(b0 + l15) * OC + (wv * 4 + o8)) * OH + g * 4;
        f32x4 a = *(const f32x4*)vb;
        f32x4 c = *(const f32x4*)(vb + 16);
        vrp[o8].x = pk2f(a.x, a.y); vrp[o8].y = pk2f(a.z, a.w);
        vrp[o8].z = pk2f(c.x, c.y); vrp[o8].w = pk2f(c.z, c.w);
    }

    // prologue: stage i0 -> buf0, load xf(i0); addresses computed inline
    {
        const char* gs = (const char*)Wp + (size_t)i0 * 65536;
#pragma unroll
        for (int r = 0; r < 4; ++r) {
            int seg = r * 16 + wv;
            gload_lds16(gs + seg * 1024 + lane * 16, smem + F_W + seg * 1024);
        }
    }
    bf16x8 xf = *(const bf16x8*)(xs + (size_t)i0 * 1024 + (size_t)(b0 + l15) * 16 + (g & 1) * 8);
    __syncthreads();

    const f32x4 fzero = {0.f, 0.f, 0.f, 0.f};
    f32x4 sacc[8];
#pragma unroll
    for (int t = 0; t < 8; ++t) sacc[t] = fzero;

    for (int ii = 0; ii < ICHUNK; ++ii) {
        const int cur = ii & 1;
        const char* wb = smem + F_W + cur * F_WBUF;
        const int i = i0 + ii;

        // issue stage(i+1) + xf(i+1) prefetch first (flies under compute)
        bf16x8 xf_n = xf;
        if (ii + 1 < ICHUNK) {
            const char* gs = (const char*)Wp + (size_t)(i + 1) * 65536;
            char* lb = smem + F_W + (cur ^ 1) * F_WBUF;
#pragma unroll
            for (int r = 0; r < 4; ++r) {
                int seg = r * 16 + wv;
                gload_lds16(gs + seg * 1024 + lane * 16, lb + seg * 1024);
            }
            xf_n = *(const bf16x8*)(xs + (size_t)(i + 1) * 1024 +
                                    (size_t)(b0 + l15) * 16 + (g & 1) * 8);
        }

        // MFMA phase: per-tile predicated A pointer (transient live range)
        f32x4 acc[8];
#pragma unroll
        for (int t = 0; t < 8; ++t) {
            int nt = wv * 128 + (t >> 1) * 32 + (t & 1) * 16;
            const char* aptr = (lane < 32)
                ? (wb + g * 32768 + (size_t)(nt + l15) * 16)
                : (smem + F_Z);
            bf16x8 af = *(const bf16x8*)aptr;
            acc[t] = __builtin_amdgcn_mfma_f32_16x16x32_bf16(af, xf, fzero, 0, 0, 0);
        }

        // Blog dots + exp in-register (no max subtraction; |Blog| <~ 12)
        float eb[4];
#pragma unroll
        for (int o8 = 0; o8 < 4; ++o8) {
            f32x4 a0 = acc[2 * o8], a1 = acc[2 * o8 + 1];
            uint4 u = vrp[o8];
            float p = a0.x * bf_lo(u.x) + a0.y * bf_hi(u.x) +
                      a0.z * bf_lo(u.y) + a0.w * bf_hi(u.y) +
                      a1.x * bf_lo(u.z) + a1.y * bf_hi(u.z) +
                      a1.z * bf_lo(u.w) + a1.w * bf_hi(u.w);
            p += __shfl_xor(p, 16);
            p += __shfl_xor(p, 32);
            eb[o8] = __expf(p);
        }
        float s4 = (eb[0] + eb[1]) + (eb[2] + eb[3]);
        if (lane < 16)
            *(float*)(smem + F_T + cur * T_BUF + l15 * T_ROW + wv * 4) = s4;

        // single full barrier: T ready + stage(i+1)/xf(i+1) landed; also
        // fences the buffer swap (r8 race fix: real compiler fence).
        __syncthreads();

        // denominator from T row b=l15 (broadcast reads)
        const char* tb = smem + F_T + cur * T_BUF + l15 * T_ROW;
        f32x4 t0 = *(const f32x4*)(tb);
        f32x4 t1 = *(const f32x4*)(tb + 16);
        f32x4 t2 = *(const f32x4*)(tb + 32);
        f32x4 t3 = *(const f32x4*)(tb + 48);
        f32x4 ts = (t0 + t1) + (t2 + t3);
        float denom = (ts.x + ts.y) + (ts.z + ts.w);
        float rd = __builtin_amdgcn_rcpf(denom);
        float c0 = eb[0] * rd, c1 = eb[1] * rd, c2 = eb[2] * rd, c3 = eb[3] * rd;
#pragma unroll
        for (int t = 0; t < 8; ++t) {
            float c = (t < 2) ? c0 : (t < 4) ? c1 : (t < 6) ? c2 : c3;
            sacc[t] += acc[t] * c;
        }
        xf = xf_n;
    }

    // write partial S: P[chunk][b][n]
#pragma unroll
    for (int t = 0; t < 8; ++t) {
        int n = wv * 128 + (t >> 1) * 32 + (t & 1) * 16 + g * 4;
        float* dst = P + ((size_t)(chunk * 64) + b0 + l15) * NN + n;
        float4 o4;
        o4.x = sacc[t].x; o4.y = sacc[t].y; o4.z = sacc[t].z; o4.w = sacc[t].w;
        *(float4*)dst = o4;
    }
}

// Sum partials over chunks, squash over j, SET or ADD into dst.
__global__ void reduce_squash(const float* __restrict__ P, float* __restrict__ dst,
                              int addmode) {
    int pr = blockIdx.x * 2 + (threadIdx.x >> 5);  // (b,o) row 0..4095
    int j = threadIdx.x & 31;
    int b = pr >> 6, o = pr & 63;
    const float* p = P + (size_t)b * NN + o * 32 + j;
    float s = 0.f;
#pragma unroll 8
    for (int c = 0; c < NCHUNK; ++c) s += p[(size_t)c * (64 * NN)];
    float nsq = s * s;
#pragma unroll
    for (int d = 16; d >= 1; d >>= 1) nsq += __shfl_xor(nsq, d);
    float nrm = sqrtf(nsq);
    float f = nrm / (1.f + nsq);   // squash: x * ||x||/(1+||x||^2)
    float outv = s * f;
    int idx = pr * 32 + j;
    if (addmode) dst[idx] += outv;
    else dst[idx] = outv;
}

extern "C" void kernel_launch(void* const* d_in, const int* in_sizes, int n_in,
                              void* d_out, int out_size, void* d_ws, size_t ws_size,
                              hipStream_t stream) {
    const float* x = (const float*)d_in[0];   // [64][2048][16]
    const float* W = (const float*)d_in[1];   // [2048][16][64][32]
    float* out = (float*)d_out;               // [64][64][32]
    char* ws = (char*)d_ws;
    // ws: xs bf16 4 MiB | P f32 32 MiB @4M | Vsum 512 KiB @36M | Wp bf16 128 MiB @40M
    unsigned short* xs = (unsigned short*)ws;
    float* P = (float*)(ws + ((size_t)4 << 20));
    float* Vsum = (float*)(ws + ((size_t)36 << 20));
    unsigned short* Wp = (unsigned short*)(ws + (((size_t)40) << 20));

    (void)hipFuncSetAttribute(reinterpret_cast<const void*>(&routed_soft),
                              hipFuncAttributeMaxDynamicSharedMemorySize, F_SMEM);

    prep_wx<<<dim3(2048), dim3(512), 0, stream>>>(W, Wp, x, xs);
    // iter 1: uniform C = 1/64 -> plain GEMM -> S1 -> V1
    uniform_gemm<<<dim3(512), dim3(512), 0, stream>>>(xs, Wp, P);
    reduce_squash<<<dim3(2048), dim3(64), 0, stream>>>(P, Vsum, 0);
    // iter 2: Blog = U.V1 -> S2 -> V2 (Vsum = V1+V2)
    routed_soft<<<dim3(256), dim3(1024), F_SMEM, stream>>>(xs, Wp, Vsum, P);
    reduce_squash<<<dim3(2048), dim3(64), 0, stream>>>(P, Vsum, 1);
    // iter 3: Blog = U.(V1+V2) -> S3 -> V3 = output
    routed_soft<<<dim3(256), dim3(1024), F_SMEM, stream>>>(xs, Wp, Vsum, P);
    reduce_squash<<<dim3(2048), dim3(64), 0, stream>>>(P, out, 0);
}